// Round 1
// 205.043 us; speedup vs baseline: 1.0093x; 1.0093x over previous
//
#include <hip/hip_runtime.h>

// Conv2d 32x128x56x56 -> 32x256x56x56, 3x3, pad 1, stride 1. fp32 I/O.
// Implicit GEMM, bf16 mfma_f32_16x16x32. K reordered as (ci_hi, kh*kw, ci_lo):
//  - X pre-transformed to NHWC bf16: B-fragment = 8 consecutive ci = 16B.
//  - W2[step][co][ci_lo] (step = ci_hi*9+khw): A-fragments load global->reg,
//    perfectly coalesced, L2-hot.
//  - Per ci_hi: x tile (4 rows x 58 cols x 32 ci, halo zeroed) staged in LDS;
//    9 khw positions read b-frags at immediate offsets -> no barriers in the
//    khw loop (8 barriers total).
// NEW this round:
//  - prep_x fully vectorized: float4 global reads, short8 (16B) global writes,
//    LDS transpose tile 32ci x 64p stride 66 (conflict-free both phases).
//    Old version used scalar 2-byte stores -> ~78us; this should be ~15us.
//  - conv: software-pipelined staging (T14): next ci_hi tile's global loads
//    are issued into registers right after the post-stage barrier, so the
//    HBM/L2 latency hides under the 9-step MFMA compute instead of being
//    exposed at every tile boundary. +16 VGPR (244 unified <= 256, still
//    2 waves/SIMD under launch_bounds(256,2)).
// Block: 256 thr = 4 waves, tile 256co x 112p (2 output rows). Wave: 4m x 7n.
// LDS col stride 40 shorts (80B): 16B-aligned ds_read_b128.

#define CIN   128
#define COUT  256
#define HWID  56
#define IMG   (HWID*HWID)     // 3136
#define NIMG  32
#define CSTR  40              // Bs ci stride (shorts), 80B
#define BROW  (58*CSTR)       // Bs row stride (shorts)

typedef __attribute__((ext_vector_type(8))) short short8;   // 8 bf16 = 4 VGPRs
typedef __attribute__((ext_vector_type(4))) float float4v;  // MFMA acc

__device__ __forceinline__ unsigned short f2bf(float f) {
    unsigned int u = __builtin_bit_cast(unsigned int, f);
    u += 0x7FFFu + ((u >> 16) & 1u);   // RNE
    return (unsigned short)(u >> 16);
}

// W2[((ci_hi*9 + kh*3 + kw)*256 + co)*32 + ci_lo] = bf16(w[co][ci_hi*32+ci_lo][kh][kw])
__global__ void prep_w_kernel(const float* __restrict__ w, unsigned short* __restrict__ W2) {
    int o = blockIdx.x * 256 + threadIdx.x;        // 294912 total
    int ci_lo = o & 31;
    int co    = (o >> 5) & 255;
    int s     = o >> 13;                           // 0..35
    int ci_hi = s / 9;
    int r9    = s - ci_hi * 9;                     // kh*3+kw
    W2[o] = f2bf(w[(co * CIN + ci_hi * 32 + ci_lo) * 9 + r9]);
}

// NCHW fp32 -> NHWC bf16 via LDS tile transpose. Tile: 32 ci x 64 p per block.
// Read: float4 (16B/lane). Write: short8 (16B/lane). LDS stride 66 shorts:
//  - write phase (uint, 4B): bank = (33*ci + 2*c4) % 32 -> 2 lanes/bank, free.
//  - read phase (u16): bank = (33*(c8*8+j) + p>>1) % 32 -> 2 lanes/bank, free.
__global__ __launch_bounds__(256) void prep_x_kernel(const float* __restrict__ x,
                                                     unsigned short* __restrict__ X2) {
    __shared__ unsigned short Ls[32 * 66];   // 4224 B
    int b  = blockIdx.x;               // n*(4*49) + cb*49 + pb
    int pb = b % 49;
    int t  = b / 49;
    int cb = t & 3;
    int n  = t >> 2;
    int p0 = pb * 64, ci0 = cb * 32;

    const float* src = x + ((long)n * CIN + ci0) * IMG + p0;
    #pragma unroll
    for (int it = 0; it < 2; ++it) {
        int flat = it * 256 + threadIdx.x;   // 0..511
        int ci_l = flat >> 4;                // 0..31
        int c4   = flat & 15;                // float4 within 64 p
        float4 v = *(const float4*)(src + ci_l * IMG + c4 * 4);   // coalesced 16B
        unsigned int lo = (unsigned int)f2bf(v.x) | ((unsigned int)f2bf(v.y) << 16);
        unsigned int hi = (unsigned int)f2bf(v.z) | ((unsigned int)f2bf(v.w) << 16);
        *(unsigned int*)(&Ls[ci_l * 66 + c4 * 4])     = lo;
        *(unsigned int*)(&Ls[ci_l * 66 + c4 * 4 + 2]) = hi;
    }
    __syncthreads();
    int p_l = threadIdx.x >> 2;   // 0..63
    int c8  = threadIdx.x & 3;    // 8-ci chunk
    unsigned short* dst = X2 + ((long)n * IMG + p0) * CIN + ci0;
    short8 o;
    #pragma unroll
    for (int j = 0; j < 8; ++j)
        o[j] = (short)Ls[(c8 * 8 + j) * 66 + p_l];
    *(short8*)(&dst[(long)p_l * CIN + c8 * 8]) = o;   // coalesced 16B
}

// Issue global loads for x tile CIHI into rx[] (no LDS write, no waits here).
#define ISSUE_TILE(CIHI) do {                                                   \
    _Pragma("unroll")                                                           \
    for (int it = 0; it < 4; ++it) {                                            \
        int idx = it * 256 + tid;      /* 0..1023, valid < 928 */               \
        int ci8 = idx & 3;                                                      \
        int rc  = idx >> 2;            /* r*58 + c, valid < 232 */              \
        uint4 v = make_uint4(0u, 0u, 0u, 0u);                                   \
        if (rc < 232) {                                                         \
            int r = rc / 58;                                                    \
            int c = rc - r * 58;                                                \
            int h = h0 - 1 + r;                                                 \
            int w = c - 1;                                                      \
            if ((unsigned)h < 56u && (unsigned)w < 56u)                         \
                v = *(const uint4*)(xnb + ((h * HWID + w) * CIN + (CIHI) * 32 + ci8 * 8)); \
        }                                                                       \
        rx[it] = v;                                                             \
    }                                                                           \
} while (0)

__global__ __launch_bounds__(256, 2)
void conv_mfma_kernel(const unsigned short* __restrict__ X2,
                      const unsigned short* __restrict__ W2,
                      float* __restrict__ out) {
    __shared__ __align__(16) unsigned short Bs[4 * BROW];   // 18560 B

    const int tid  = threadIdx.x;
    const int lane = tid & 63;
    const int wv   = tid >> 6;
    const int l15  = lane & 15;
    const int quad = lane >> 4;

    const int pt    = blockIdx.x;      // 0..895
    const int n_img = pt / 28;
    const int h0    = (pt % 28) * 2;   // output rows h0, h0+1

    // per-lane b-frag bases (short index into Bs), one per n-tile
    int boff[7];
    #pragma unroll
    for (int n = 0; n < 7; ++n) {
        int p    = n * 16 + l15;
        int prow = (p >= 56) ? 1 : 0;
        int pcol = p - prow * 56;
        boff[n]  = (prow * 58 + pcol) * CSTR + quad * 8;
    }

    // a-frag base: W2[step][co][ci_lo], co = wv*64 + m*16 + l15, ci_lo = quad*8+j
    const unsigned short* wbase = W2 + (wv * 64 + l15) * 32 + quad * 8;

    float4v acc[4][7];
    #pragma unroll
    for (int m = 0; m < 4; ++m)
        #pragma unroll
        for (int n = 0; n < 7; ++n)
            acc[m][n] = (float4v){0.f, 0.f, 0.f, 0.f};

    const unsigned short* xnb = X2 + (long)n_img * (IMG * CIN);

    uint4 rx[4];
    ISSUE_TILE(0);                      // prologue: tile 0 loads in flight

    for (int ci_hi = 0; ci_hi < 4; ++ci_hi) {
        __syncthreads();   // previous iteration's readers done with Bs

        // ---- drain rx (vmcnt) and write staged tile to LDS ----
        #pragma unroll
        for (int it = 0; it < 4; ++it) {
            int idx = it * 256 + tid;
            int rc  = idx >> 2;
            if (rc < 232) {
                int ci8 = idx & 3;
                *(uint4*)(&Bs[rc * CSTR + ci8 * 8]) = rx[it];
            }
        }
        __syncthreads();

        // ---- prefetch next tile: loads fly under the 9-step compute ----
        if (ci_hi < 3) ISSUE_TILE(ci_hi + 1);

        // ---- 9 khw positions, NO barriers (Bs read-only here) ----
        #pragma unroll
        for (int khw = 0; khw < 9; ++khw) {
            const int kh = khw / 3, kw = khw - (khw / 3) * 3;
            const int step = ci_hi * 9 + khw;
            short8 a[4], bfr[7];
            #pragma unroll
            for (int m = 0; m < 4; ++m)
                a[m] = *(const short8*)(wbase + step * 8192 + m * 512);
            #pragma unroll
            for (int n = 0; n < 7; ++n)
                bfr[n] = *(const short8*)(&Bs[boff[n] + (kh * 58 + kw) * CSTR]);
            #pragma unroll
            for (int m = 0; m < 4; ++m)
                #pragma unroll
                for (int n = 0; n < 7; ++n)
                    acc[m][n] = __builtin_amdgcn_mfma_f32_16x16x32_bf16(a[m], bfr[n], acc[m][n], 0, 0, 0);
        }
    }

    // ---- epilogue: C/D layout col(p)=lane&15, row(co)=quad*4+reg ----
    float* obase = out + (long)n_img * (COUT * IMG) + h0 * HWID;
    #pragma unroll
    for (int m = 0; m < 4; ++m) {
        #pragma unroll
        for (int r = 0; r < 4; ++r) {
            int co = wv * 64 + m * 16 + quad * 4 + r;
            float* orow = obase + (long)co * IMG;
            #pragma unroll
            for (int n = 0; n < 7; ++n)
                orow[n * 16 + l15] = acc[m][n][r];
        }
    }
}

extern "C" void kernel_launch(void* const* d_in, const int* in_sizes, int n_in,
                              void* d_out, int out_size, void* d_ws, size_t ws_size,
                              hipStream_t stream) {
    const float* x  = (const float*)d_in[0];
    const float* wt = (const float*)d_in[1];
    float* out = (float*)d_out;

    unsigned short* X2 = (unsigned short*)d_ws;            // 12,845,056 shorts (NHWC bf16)
    unsigned short* W2 = X2 + (long)NIMG * CIN * IMG;      // 294,912 shorts

    prep_x_kernel<<<NIMG * 4 * 49, 256, 0, stream>>>(x, X2);
    prep_w_kernel<<<(COUT * CIN * 9) / 256, 256, 0, stream>>>(wt, W2);
    conv_mfma_kernel<<<896, 256, 0, stream>>>(X2, W2, out);
}